// Round 13
// baseline (316.245 us; speedup 1.0000x reference)
//
#include <hip/hip_runtime.h>
#include <hip/hip_bf16.h>
#include <cstdint>
#include <cstddef>

// Problem constants (fixed by the reference)
#define N_NODES   50000
#define N_EDGES   640000
#define ETOT      (N_EDGES + N_NODES)   // edges + self loops = 690000
#define IN_DIM    128
#define HID       64
#define HEADS     8
#define F1        (HEADS * HID)         // 512
#define OUT_DIM   2
#define N_GRAPHS  64
#define NEG_SLOPE 0.2f
#define CAP       64   // in-degree ~ Poisson(12.8)+1 self-loop; P(deg>63)~1e-24

typedef __attribute__((ext_vector_type(8))) short s8v;    // 8 x bf16 (4 VGPR)
typedef __attribute__((ext_vector_type(4))) float f32x4;  // MFMA accumulator
typedef __attribute__((ext_vector_type(2))) float f32x2;  // packed f32 pair
typedef unsigned char uchar;
typedef unsigned int  uint;
typedef unsigned long long u64;

__device__ __forceinline__ float leakyf(float x) { return x > 0.f ? x : NEG_SLOPE * x; }
__device__ __forceinline__ float eluf(float x)   { return x > 0.f ? x : __expf(x) - 1.f; }

__device__ __forceinline__ ushort f2bf(float f) {
    union { float f; uint32_t i; } c; c.f = f;
    uint32_t r = c.i + 0x7FFFu + ((c.i >> 16) & 1u);   // round-to-nearest-even
    return (ushort)(r >> 16);
}
// HW fp8 e4m3 (OCP on gfx950); sel args must be immediates -> templates
template<int SEL>
__device__ __forceinline__ float fp8f(uint w) {
    return __builtin_amdgcn_cvt_f32_fp8(w, SEL);
}
template<bool HI>
__device__ __forceinline__ f32x2 pk8(uint w) {
    return __builtin_amdgcn_cvt_pk_f32_fp8(w, HI);   // 2 fp8 -> 2 f32, 1 instr
}
// column permutation within a 64-block: permuted pos q holds original col
// orig64(q) = ((q&3)<<4) | (q>>2)   (see GEMM epilogue packing)
__device__ __forceinline__ int orig64(int q) { return ((q & 3) << 4) | (q >> 2); }

// ----------------------------------- fused prep: padded-CSR fill + weights
#define W1_ITEMS  (F1 * IN_DIM)                 // 65536
#define W2_ITEMS  (HID * F1)                    // 32768
#define PM_ITEMS  (F1 + HID + HID * OUT_DIM)    // 512 + 64 + 128 = 704
#define PREP_ITEMS (ETOT + W1_ITEMS + W2_ITEMS + PM_ITEMS)

__global__ __launch_bounds__(256) void prep_fill(const int* __restrict__ srcI,
                                                 const int* __restrict__ dstI,
                                                 int* __restrict__ counts,
                                                 ushort* __restrict__ csrp,
                                                 const float* __restrict__ W1,
                                                 const float* __restrict__ W2,
                                                 const float* __restrict__ b1,
                                                 const float* __restrict__ b2,
                                                 const float* __restrict__ fcw,
                                                 ushort* __restrict__ W1T,
                                                 ushort* __restrict__ W2T,
                                                 float* __restrict__ b1p,
                                                 float* __restrict__ b2p,
                                                 float* __restrict__ fcwp) {
    int i = blockIdx.x * 256 + threadIdx.x;
    if (i < ETOT) {
        int s, d;
        if (i < N_EDGES) { s = srcI[i]; d = dstI[i]; }
        else             { s = d = i - N_EDGES; }
        int slot = atomicAdd(&counts[d], 1);
        if (slot < CAP) csrp[d * CAP + slot] = (ushort)s;
    } else if (i < ETOT + W1_ITEMS) {
        int idx = i - ETOT;
        int n = idx >> 7, k = idx & 127;         // W1T[n][k] = W1[k][n]
        W1T[idx] = f2bf(W1[(size_t)k * F1 + n]);
    } else if (i < ETOT + W1_ITEMS + W2_ITEMS) {
        int idx = i - ETOT - W1_ITEMS;
        int n = idx >> 9, kp = idx & 511;        // permuted K (z1 layout)
        int ko = (kp & 448) | orig64(kp & 63);
        W2T[idx] = f2bf(W2[(size_t)ko * HID + n]);
    } else if (i < PREP_ITEMS) {
        int j = i - ETOT - W1_ITEMS - W2_ITEMS;
        if (j < F1) {                            // permuted layer-1 bias
            b1p[j] = b1[(j & ~63) | orig64(j & 63)];
        } else if (j < F1 + HID) {               // permuted layer-2 bias
            int q = j - F1;
            b2p[q] = b2[orig64(q)];
        } else {                                 // permuted fc weights
            int q = j - F1 - HID;
            int ch = q >> 1, o = q & 1;
            fcwp[q] = fcw[orig64(ch) * OUT_DIM + o];
        }
    }
}

// ---------------------------------------------------------------- bf16 GEMM
// C[M,N] = A[M,K] @ BT[N,K]^T, f32 acc, fp8 e4m3 out in PERMUTED col layout.
// AH!=1 (layer 1): C8 stored PAIR-MAJOR [pair][node][128] (head-pair slices
// for the XCD-sliced aggregation); AH==1: row-major [node][64].
// AF32: A is f32, cast to bf16 during LDS staging. Bijective XCD swizzle.
template<int BM, int BN, int BK, int AH, bool AF32>
__global__ __launch_bounds__(256) void gemm_att(const void* __restrict__ Av,
                                                const ushort* __restrict__ BT,
                                                uchar* __restrict__ C8,
                                                int M, int N, int K,
                                                const float* __restrict__ att_s,
                                                const float* __restrict__ att_d,
                                                float* __restrict__ as_o,
                                                float* __restrict__ ad_o) {
    // bijective XCD swizzle (m204)
    int nwg = gridDim.x;
    int q = nwg >> 3, r = nwg & 7;
    int xcd = blockIdx.x & 7, loc = blockIdx.x >> 3;
    int sid = (xcd < r) ? (xcd * (q + 1) + loc)
                        : (r * (q + 1) + (xcd - r) * q + loc);
    int ncb = N / BN;
    int bx = sid % ncb;          // col block (head)
    int by = sid / ncb;          // row panel

    __shared__ ushort As[BM * BK];   // XOR-swizzled
    __shared__ ushort Bs[BN * BK];
    const int t    = threadIdx.x;
    const int row0 = by * BM;
    const int col0 = bx * BN;
    const int lane = t & 63;
    const int wr   = t >> 6;                 // 0..3, wave row band
    constexpr int FR = BM / 64;              // fragments per wave row band

    f32x4 acc[FR][4];
    #pragma unroll
    for (int i = 0; i < FR; ++i)
        #pragma unroll
        for (int j = 0; j < 4; ++j)
            acc[i][j] = (f32x4){0.f, 0.f, 0.f, 0.f};

    constexpr int A_IT = BM * BK / 8 / 256;  // 16B(bf16) chunks per thread
    constexpr int B_IT = BN * BK / 8 / 256;

    for (int k0 = 0; k0 < K; k0 += BK) {
        #pragma unroll
        for (int i = 0; i < A_IT; ++i) {
            int ch  = t + 256 * i;
            int rr  = ch >> 3;               // BK*2/16 = 8 chunks per row
            int c16 = ch & 7;
            int gr = row0 + rr;
            uint4 v = make_uint4(0u, 0u, 0u, 0u);
            if constexpr (AF32) {
                const float* Af = (const float*)Av;
                if (gr < M) {
                    const float* pr = Af + (size_t)gr * K + k0 + c16 * 8;
                    float4 f0 = *reinterpret_cast<const float4*>(pr);
                    float4 f1 = *reinterpret_cast<const float4*>(pr + 4);
                    v.x = ((uint)f2bf(f0.y) << 16) | f2bf(f0.x);
                    v.y = ((uint)f2bf(f0.w) << 16) | f2bf(f0.z);
                    v.z = ((uint)f2bf(f1.y) << 16) | f2bf(f1.x);
                    v.w = ((uint)f2bf(f1.w) << 16) | f2bf(f1.z);
                }
            } else {
                const ushort* Ab = (const ushort*)Av;
                if (gr < M)
                    v = *reinterpret_cast<const uint4*>(Ab + (size_t)gr * K + k0 + c16 * 8);
            }
            int off = (ch * 16) ^ ((rr & 7) << 4);
            *reinterpret_cast<uint4*>(reinterpret_cast<char*>(As) + off) = v;
        }
        #pragma unroll
        for (int i = 0; i < B_IT; ++i) {
            int ch  = t + 256 * i;
            int rr  = ch >> 3;
            int c16 = ch & 7;
            uint4 v = *reinterpret_cast<const uint4*>(BT + (size_t)(col0 + rr) * K + k0 + c16 * 8);
            int off = (ch * 16) ^ ((rr & 7) << 4);
            *reinterpret_cast<uint4*>(reinterpret_cast<char*>(Bs) + off) = v;
        }
        __syncthreads();
        #pragma unroll
        for (int kk = 0; kk < BK; kk += 32) {
            s8v af[FR], bf[4];
            #pragma unroll
            for (int fr = 0; fr < FR; ++fr) {
                int rr  = wr * (FR * 16) + fr * 16 + (lane & 15);
                int off = (rr * (BK * 2) + kk * 2 + (lane >> 4) * 16) ^ ((rr & 7) << 4);
                af[fr] = *reinterpret_cast<const s8v*>(reinterpret_cast<const char*>(As) + off);
            }
            #pragma unroll
            for (int fc = 0; fc < 4; ++fc) {
                int rr  = fc * 16 + (lane & 15);
                int off = (rr * (BK * 2) + kk * 2 + (lane >> 4) * 16) ^ ((rr & 7) << 4);
                bf[fc] = *reinterpret_cast<const s8v*>(reinterpret_cast<const char*>(Bs) + off);
            }
            #pragma unroll
            for (int fr = 0; fr < FR; ++fr)
                #pragma unroll
                for (int fc = 0; fc < 4; ++fc)
                    acc[fr][fc] = __builtin_amdgcn_mfma_f32_16x16x32_bf16(af[fr], bf[fc], acc[fr][fc], 0, 0, 0);
        }
        __syncthreads();
    }

    // att vectors for this head (col block), at this lane's 4 ORIGINAL cols
    float avs[4], avd[4];
    const float* asp = att_s + bx * BN;
    const float* adp = att_d + bx * BN;
    #pragma unroll
    for (int fc = 0; fc < 4; ++fc) {
        avs[fc] = asp[fc * 16 + (lane & 15)];
        avd[fc] = adp[fc * 16 + (lane & 15)];
    }

    // epilogue: C/D layout col=lane&15, row=(lane>>4)*4+reg  [m89-verified]
    // pack 4 fp8 bytes (fc=0..3) into one u32 at permuted pos l16*4.
    #pragma unroll
    for (int fr = 0; fr < FR; ++fr) {
        #pragma unroll
        for (int j = 0; j < 4; ++j) {
            int row = row0 + wr * (FR * 16) + fr * 16 + (lane >> 4) * 4 + j;
            if (row < M) {
                uint pk = __builtin_amdgcn_cvt_pk_fp8_f32(acc[fr][0][j], acc[fr][1][j], 0u, false);
                pk = __builtin_amdgcn_cvt_pk_fp8_f32(acc[fr][2][j], acc[fr][3][j], pk, true);
                if constexpr (AH != 1) {
                    // pair-major: [pair][node][128]; pair = bx>>1, half = bx&1
                    *reinterpret_cast<uint*>(C8 + (size_t)(bx >> 1) * N_NODES * 128
                                             + (size_t)row * 128 + (bx & 1) * 64
                                             + (lane & 15) * 4) = pk;
                } else {
                    *reinterpret_cast<uint*>(C8 + (size_t)row * 64 + (lane & 15) * 4) = pk;
                }
                float sv = 0.f, dv = 0.f;
                #pragma unroll
                for (int fc = 0; fc < 4; ++fc) {
                    float c = acc[fr][fc][j];
                    sv = fmaf(c, avs[fc], sv);
                    dv = fmaf(c, avd[fc], dv);
                }
                #pragma unroll
                for (int off = 1; off < 16; off <<= 1) {
                    sv += __shfl_xor(sv, off);
                    dv += __shfl_xor(dv, off);
                }
                if ((lane & 15) == 0) {
                    as_o[(size_t)row * AH + bx] = sv;
                    ad_o[(size_t)row * AH + bx] = dv;
                }
            }
        }
    }
}

// ------------------------------------------- layer-1 aggregation (8 heads)
// XCD-sliced by head pair: block b handles pair = b&3 for 4 dsts (one per
// wave). With round-robin blockIdx->XCD dispatch, pair p lands on XCDs
// {p, p+4} only -> per-XCD h1p footprint = one 6.4 MB slice (vs 21 MB).
// Branchless padded edge loop (pad w=0, pad src=0) for clean pipelining.
__global__ __launch_bounds__(256) void gat_agg1(const uchar* __restrict__ h1p,
                                                const float* __restrict__ as,
                                                const float* __restrict__ ad,
                                                const int* __restrict__ counts,
                                                const ushort* __restrict__ csrp,
                                                const float* __restrict__ b1p,
                                                ushort* __restrict__ z) {
    __shared__ float lds_w[4][2][CAP];
    int tid  = threadIdx.x;
    int wid  = tid >> 6;
    int lane = tid & 63;
    int pair = blockIdx.x & 3;                    // head pair (XCD slice)
    int dst  = (blockIdx.x >> 2) * 4 + wid;       // 12500 groups x 4 waves
    int cnt  = min(counts[dst], CAP);
    int half = lane >> 5;                         // 0: head 2p, 1: head 2p+1

    // ---- phase 1: lane = edge; weights for this pair's 2 heads
    int myidx = (lane < cnt) ? (int)csrp[(size_t)dst * CAP + lane] : 0;
    f32x2 av = *reinterpret_cast<const f32x2*>(as + (size_t)myidx * HEADS + pair * 2);
    f32x2 dv = *reinterpret_cast<const f32x2*>(ad + (size_t)dst * HEADS + pair * 2);
    float w0 = (lane < cnt) ? __expf(leakyf(av[0] + dv[0])) : 0.f;
    float w1 = (lane < cnt) ? __expf(leakyf(av[1] + dv[1])) : 0.f;
    lds_w[wid][0][lane] = w0;
    lds_w[wid][1][lane] = w1;
    // same wave produces & consumes -> lgkmcnt ordering, no barrier needed

    // ---- phase 2: 2B/lane gathers of the 128B pair row, 4-deep, branchless
    f32x2 acc = (f32x2){0.f, 0.f};
    float den = 0.f;
    const uchar* hb = h1p + (size_t)pair * N_NODES * 128 + lane * 2;
    int cntR = (cnt + 3) & ~3;
    for (int j0 = 0; j0 < cntR; j0 += 4) {
        int s0 = __shfl(myidx, j0);
        int s1 = __shfl(myidx, j0 + 1);
        int s2 = __shfl(myidx, j0 + 2);
        int s3 = __shfl(myidx, j0 + 3);
        uint v0 = *reinterpret_cast<const ushort*>(hb + (size_t)s0 * 128);
        uint v1 = *reinterpret_cast<const ushort*>(hb + (size_t)s1 * 128);
        uint v2 = *reinterpret_cast<const ushort*>(hb + (size_t)s2 * 128);
        uint v3 = *reinterpret_cast<const ushort*>(hb + (size_t)s3 * 128);
        float u0 = lds_w[wid][half][j0];
        float u1 = lds_w[wid][half][j0 + 1];
        float u2 = lds_w[wid][half][j0 + 2];
        float u3 = lds_w[wid][half][j0 + 3];
        den += (u0 + u1) + (u2 + u3);
        acc += pk8<false>(v0) * (f32x2){u0, u0};
        acc += pk8<false>(v1) * (f32x2){u1, u1};
        acc += pk8<false>(v2) * (f32x2){u2, u2};
        acc += pk8<false>(v3) * (f32x2){u3, u3};
    }
    float inv = 1.f / (den + 1e-16f);
    int qb = pair * 128 + lane * 2;               // permuted global position
    float r0 = eluf(acc[0] * inv + b1p[qb]);
    float r1 = eluf(acc[1] * inv + b1p[qb + 1]);
    uint w = ((uint)f2bf(r1) << 16) | f2bf(r0);
    *reinterpret_cast<uint*>(z + (size_t)dst * F1 + qb) = w;
}

// --------------------- layer-2 aggregation (1 head) + fused graph pooling
// branchless padded edge loop; block-reduces by graph id, atomics to psum.
__global__ __launch_bounds__(256) void gat_agg2(const uchar* __restrict__ h8,
                                                const float* __restrict__ as,
                                                const float* __restrict__ ad,
                                                const int* __restrict__ counts,
                                                const ushort* __restrict__ csrp,
                                                const float* __restrict__ b2p,
                                                const int* __restrict__ batch,
                                                float* __restrict__ psum) {
    __shared__ float shz[4][HID];
    __shared__ int   shg[4];
    int tid  = threadIdx.x;
    int wid  = tid >> 6;
    int dst  = (blockIdx.x * 256 + tid) >> 6;     // grid exact: 12500 blocks
    int lane = tid & 63;
    int cnt = min(counts[dst], CAP);
    float adv = ad[dst];

    int myidx = (lane < cnt) ? (int)csrp[(size_t)dst * CAP + lane] : 0;
    float wl  = (lane < cnt) ? __expf(leakyf(as[myidx] + adv)) : 0.f;
    float den = wl;
    #pragma unroll
    for (int off = 32; off > 0; off >>= 1) den += __shfl_xor(den, off);

    float acc = 0.f;
    int cntR = (cnt + 3) & ~3;
    for (int j0 = 0; j0 < cntR; j0 += 4) {
        int s0 = __shfl(myidx, j0);
        int s1 = __shfl(myidx, j0 + 1);
        int s2 = __shfl(myidx, j0 + 2);
        int s3 = __shfl(myidx, j0 + 3);
        float w0 = __shfl(wl, j0);
        float w1 = __shfl(wl, j0 + 1);
        float w2 = __shfl(wl, j0 + 2);
        float w3 = __shfl(wl, j0 + 3);
        uint b0 = h8[(size_t)s0 * HID + lane];
        uint b1 = h8[(size_t)s1 * HID + lane];
        uint b2 = h8[(size_t)s2 * HID + lane];
        uint b3 = h8[(size_t)s3 * HID + lane];
        acc = fmaf(w0, fp8f<0>(b0), acc);
        acc = fmaf(w1, fp8f<0>(b1), acc);
        acc = fmaf(w2, fp8f<0>(b2), acc);
        acc = fmaf(w3, fp8f<0>(b3), acc);
    }
    float v = eluf(acc / (den + 1e-16f) + b2p[lane]);   // permuted channel

    shz[wid][lane] = v;
    if (lane == 0) shg[wid] = batch[dst];
    __syncthreads();
    if (wid == 0) {
        float s = shz[0][lane];
        int   g = shg[0];
        #pragma unroll
        for (int i = 1; i < 4; ++i) {
            if (shg[i] == g) s += shz[i][lane];
            else {
                atomicAdd(&psum[(size_t)g * HID + lane], s);
                s = shz[i][lane]; g = shg[i];
            }
        }
        atomicAdd(&psum[(size_t)g * HID + lane], s);
    }
}

// ----------------------------- final: mean (counts via batch bisect) + FC
__global__ __launch_bounds__(128) void final_fc(const float* __restrict__ psum,
                                                const int* __restrict__ batch,
                                                const float* __restrict__ fcwp,
                                                const float* __restrict__ fc_b,
                                                float* __restrict__ out) {
    int t = threadIdx.x;                 // 128 = 64 graphs x 2 outputs
    int g = t >> 1, o = t & 1;
    auto lb = [&](int key) {
        int lo = 0, hi = N_NODES;
        while (lo < hi) { int mid = (lo + hi) >> 1; if (batch[mid] < key) lo = mid + 1; else hi = mid; }
        return lo;
    };
    float cnt = fmaxf((float)(lb(g + 1) - lb(g)), 1.0f);
    float s = 0.f;
    for (int c = 0; c < HID; ++c)
        s += psum[(size_t)g * HID + c] * fcwp[c * OUT_DIM + o];
    out[g * OUT_DIM + o] = s / cnt + fc_b[o];
}

// ---------------------------------------------------------------- launcher
extern "C" void kernel_launch(void* const* d_in, const int* in_sizes, int n_in,
                              void* d_out, int out_size, void* d_ws, size_t ws_size,
                              hipStream_t stream) {
    const float* x    = (const float*)d_in[0];
    const float* W1   = (const float*)d_in[1];
    const float* at_s1= (const float*)d_in[2];
    const float* at_d1= (const float*)d_in[3];
    const float* b1   = (const float*)d_in[4];
    const float* W2   = (const float*)d_in[5];
    const float* at_s2= (const float*)d_in[6];
    const float* at_d2= (const float*)d_in[7];
    const float* b2   = (const float*)d_in[8];
    const float* fcw  = (const float*)d_in[9];
    const float* fcb  = (const float*)d_in[10];
    const int*   ei   = (const int*)d_in[11];
    const int*   batch= (const int*)d_in[12];
    float* out = (float*)d_out;

    char* p = (char*)d_ws;
    auto alloc = [&](size_t bytes) {
        char* r = p;
        p += (bytes + 255) & ~size_t(255);
        return r;
    };
    // zero-region first: counts | psum  (single memset)
    int*    counts= (int*)alloc((size_t)N_NODES * 4);
    float*  psum  = (float*)alloc((size_t)N_GRAPHS * HID * 4);
    size_t zero_bytes = (size_t)(p - (char*)counts);

    ushort* W1T   = (ushort*)alloc((size_t)F1 * IN_DIM * 2);
    ushort* W2T   = (ushort*)alloc((size_t)HID * F1 * 2);
    float*  b1p   = (float*)alloc((size_t)F1 * 4);
    float*  b2p   = (float*)alloc((size_t)HID * 4);
    float*  fcwp  = (float*)alloc((size_t)HID * OUT_DIM * 4);
    uchar*  h1    = (uchar*)alloc((size_t)N_NODES * F1);       // fp8, pair-major
    ushort* z1    = (ushort*)alloc((size_t)N_NODES * F1 * 2);  // bf16, permuted
    uchar*  h2    = (uchar*)alloc((size_t)N_NODES * HID);      // fp8, permuted
    float*  as1   = (float*)alloc((size_t)N_NODES * HEADS * 4);
    float*  ad1   = (float*)alloc((size_t)N_NODES * HEADS * 4);
    float*  as2   = (float*)alloc((size_t)N_NODES * 4);
    float*  ad2   = (float*)alloc((size_t)N_NODES * 4);
    ushort* csrp  = (ushort*)alloc((size_t)N_NODES * CAP * 2);

    const int* srcI = ei;
    const int* dstI = ei + N_EDGES;

    (void)hipMemsetAsync(counts, 0, zero_bytes, stream);

    // fused: padded-CSR fill + weight transposes + permuted aux (1 kernel)
    prep_fill<<<(PREP_ITEMS + 255) / 256, 256, 0, stream>>>(
        srcI, dstI, counts, csrp, W1, W2, b1, b2, fcw, W1T, W2T, b1p, b2p, fcwp);

    // Layer 1: h1(fp8, pair-major) = x(f32) @ W1; as1/ad1 fused; XCD swizzle
    int nwg1 = (F1 / 64) * ((N_NODES + 127) / 128);   // 8 * 391 = 3128
    gemm_att<128, 64, 64, HEADS, true><<<nwg1, 256, 0, stream>>>(
        x, W1T, h1, N_NODES, F1, IN_DIM, at_s1, at_d1, as1, ad1);

    // layer-1 aggregation: XCD-sliced by head pair (4 blocks per dst group)
    gat_agg1<<<(N_NODES / 4) * 4, 256, 0, stream>>>(h1, as1, ad1, counts, csrp, b1p, z1);

    // Layer 2: h2(fp8,perm) = z1(bf16,perm) @ W2T(perm-K); as2/ad2 fused
    int nwg2 = 1 * ((N_NODES + 63) / 64);             // 782 (BM=64, 3/CU)
    gemm_att<64, 64, 64, 1, false><<<nwg2, 256, 0, stream>>>(
        z1, W2T, h2, N_NODES, HID, F1, at_s2, at_d2, as2, ad2);

    // layer-2 aggregation + fused graph pooling (atomics into psum)
    gat_agg2<<<N_NODES / 4, 256, 0, stream>>>(h2, as2, ad2, counts, csrp, b2p, batch, psum);

    // final: mean + FC (single tiny block)
    final_fc<<<1, 128, 0, stream>>>(psum, batch, fcwp, fcb, out);
}